// Round 11
// baseline (428.862 us; speedup 1.0000x reference)
//
#include <hip/hip_runtime.h>
#include <hip/hip_bf16.h>
#include <stdint.h>

#define NN 100000      // nodes
#define NE 1600000     // edges
#define INF 256        // in feats
#define HF 128         // hidden feats
#define NC 40          // classes
#define NNP 100352     // NN padded to multiple of 512
#define NBUK 1568      // NNP / 64 buckets (64 nodes per bucket)
#define BKSH 6         // bucket = node >> 6
#define NBLK 256       // blocks for bfill (all CUs)
#define CHUNK 6250     // edges per block (256 * 6250 == NE)
#define SA 1536        // edgesA words per bucket window (mean 1021, 16 sigma)
#define SB 1536        // bytesB bytes per bucket window

typedef unsigned short ushort_t;
typedef unsigned int uint_t;
typedef unsigned char uchar_t;
typedef __attribute__((ext_vector_type(8))) short short8;   // 8 bf16 (4 VGPR)
typedef __attribute__((ext_vector_type(4))) float f32x4;

__device__ __forceinline__ float bflo(uint_t u) {
    union { uint_t i; float f; } v; v.i = u << 16; return v.f;
}
__device__ __forceinline__ float bfhi(uint_t u) {
    union { uint_t i; float f; } v; v.i = u & 0xffff0000u; return v.f;
}
__device__ __forceinline__ uint_t f2bf(float f) {
    __hip_bfloat16 h = __float2bfloat16(f);
    return (uint_t)*reinterpret_cast<ushort_t*>(&h);
}

// ---- init strided bucket cursors ----
__global__ void k_binit(uint_t* __restrict__ cursA, uint_t* __restrict__ cursB) {
    int t = blockIdx.x * 256 + threadIdx.x;
    if (t < NBUK) { cursA[t] = (uint_t)t * SA; cursB[t] = (uint_t)t * SB; }
}

// ---- bucket scatter into strided windows + W1/W2 fragment conversion ----
// 1024 threads/block (16 waves/CU): pure gather/scatter latency kernel.
// W1f layout: (k,n) -> (((ks*8+ct)*4+q)*16+ln)*8 + j  (ks=k/32,q=(k/8)%4,j=k%8,ct=n/16,ln=n&15)
// W2f layout: K=128, N padded 40->48: (((ks*3+ct)*4+q)*16+ln)*8 + j
__launch_bounds__(1024)
__global__ void k_bfill(const int* __restrict__ src, const int* __restrict__ dst,
                        uint_t* __restrict__ cursA, uint_t* __restrict__ cursB,
                        uint_t* __restrict__ edgesA, uchar_t* __restrict__ bytesB,
                        const float* __restrict__ W1, ushort_t* __restrict__ W1f,
                        const float* __restrict__ W2, ushort_t* __restrict__ W2f) {
    __shared__ uint_t hA[NBUK], hB[NBUK];   // 12.5 KB
    for (int t = threadIdx.x; t < NBUK; t += 1024) { hA[t] = 0; hB[t] = 0; }

    // fused one-time weight conversion
    int i = blockIdx.x * 1024 + threadIdx.x;
    if (i < INF * HF) {
        int k = i >> 7, n = i & 127;
        int ks = k >> 5, q = (k >> 3) & 3, j = k & 7;
        int ct = n >> 4, ln = n & 15;
        W1f[(((ks * 8 + ct) * 4 + q) * 16 + ln) * 8 + j] = (ushort_t)f2bf(W1[i]);
    }
    if (i < HF * 48) {
        int k = i / 48, n = i % 48;
        int ks = k >> 5, q = (k >> 3) & 3, j = k & 7;
        int ct = n >> 4, ln = n & 15;
        float v = (n < NC) ? W2[k * NC + n] : 0.0f;
        W2f[(((ks * 3 + ct) * 4 + q) * 16 + ln) * 8 + j] = (ushort_t)f2bf(v);
    }
    __syncthreads();

    const int beg = blockIdx.x * CHUNK, end = beg + CHUNK;
    for (int e = beg + threadIdx.x; e < end; e += 1024) {
        atomicAdd(&hA[(uint_t)dst[e] >> BKSH], 1u);
        atomicAdd(&hB[(uint_t)src[e] >> BKSH], 1u);
    }
    __syncthreads();
    for (int t = threadIdx.x; t < NBUK; t += 1024) {
        uint_t c = hA[t];
        hA[t] = c ? atomicAdd(&cursA[t], c) : 0;
        c = hB[t];
        hB[t] = c ? atomicAdd(&cursB[t], c) : 0;
    }
    __syncthreads();
    for (int e = beg + threadIdx.x; e < end; e += 1024) {
        uint_t d = (uint_t)dst[e], s = (uint_t)src[e];
        uint_t pA = atomicAdd(&hA[d >> BKSH], 1u);     // LDS cursor
        edgesA[pA] = ((d & 63u) << 17) | s;            // 23-bit packed (dstLow, src)
        uint_t pB = atomicAdd(&hB[s >> BKSH], 1u);     // LDS cursor
        bytesB[pB] = (uchar_t)(s & 63u);
    }
}

// ---- per-bucket finish (bscan fused) ----
__launch_bounds__(256)
__global__ void k_bfinish(const uint_t* __restrict__ cursA, const uint_t* __restrict__ cursB,
                          const uint_t* __restrict__ edgesA, const uchar_t* __restrict__ bytesB,
                          int* __restrict__ row_ptr, int* __restrict__ srcs,
                          float* __restrict__ isq_d, float* __restrict__ isq_s) {
    __shared__ uint_t red[256];
    __shared__ uint_t h[64], sc[64], cur[64];
    const int b = blockIdx.x, t = threadIdx.x;

    // fused exclusive bucket scan: obase = sum_{i<b} (cursA[i] - i*SA)
    uint_t acc = 0;
    for (int i = t; i < b; i += 256) acc += cursA[i] - (uint_t)i * SA;
    red[t] = acc;
    __syncthreads();
    for (int off = 128; off > 0; off >>= 1) {
        if (t < off) red[t] += red[t + off];
        __syncthreads();
    }
    const uint_t obase = red[0];

    if (t < 64) h[t] = 0;
    __syncthreads();
    const uint_t begI = (uint_t)b * SA;
    const uint_t endI = cursA[b];
    for (uint_t e = begI + t; e < endI; e += 256)
        atomicAdd(&h[(edgesA[e] >> 17) & 63u], 1u);
    __syncthreads();
    uint_t v = (t < 64) ? h[t] : 0;
    if (t < 64) sc[t] = v;
    __syncthreads();
    for (int off = 1; off < 64; off <<= 1) {
        uint_t tv = (t >= off && t < 64) ? sc[t - off] : 0;
        __syncthreads();
        if (t < 64) sc[t] += tv;
        __syncthreads();
    }
    if (t < 64) {
        uint_t excl = sc[t] - v;
        row_ptr[b * 64 + t] = (int)(obase + excl);
        isq_d[b * 64 + t] = rsqrtf(fmaxf((float)v, 1.0f));
        cur[t] = excl;
    }
    __syncthreads();
    for (uint_t e = begI + t; e < endI; e += 256) {
        uint_t u = edgesA[e];
        uint_t p = atomicAdd(&cur[(u >> 17) & 63u], 1u);
        srcs[obase + p] = (int)(u & 0x1FFFFu);
    }
    __syncthreads();
    if (t < 64) h[t] = 0;
    __syncthreads();
    const uint_t begB = (uint_t)b * SB;
    const uint_t endB = cursB[b];
    for (uint_t e = begB + t; e < endB; e += 256)
        atomicAdd(&h[bytesB[e]], 1u);
    __syncthreads();
    if (t < 64) isq_s[b * 64 + t] = rsqrtf(fmaxf((float)h[t], 1.0f));
}

// ---- GEMM1 (MFMA): Hfs[slice][N][16 feats](bf16) = slices of (X@W1)*isq_s ----
// Identical compute to R10; only the H store address changed to slice-major:
// feat f = ct*16+ln of row r  ->  Hfs ushort offset (ct*NN + r)*16 + ln.
__launch_bounds__(256, 4)
__global__ void k_gemm1(const float* __restrict__ X, const ushort_t* __restrict__ W1f,
                        const float* __restrict__ isq_s, ushort_t* __restrict__ H) {
    const int wv = threadIdx.x >> 6;
    const int lane = threadIdx.x & 63;
    const int ln = lane & 15;
    const int q  = lane >> 4;
    const int r0 = blockIdx.x * 64 + wv * 16;
    const int rm = min(r0 + ln, NN - 1);     // A row for this lane (m = ln)

    f32x4 acc[8];
#pragma unroll
    for (int ct = 0; ct < 8; ++ct) acc[ct] = (f32x4){0.f, 0.f, 0.f, 0.f};

    const float* xp = &X[(size_t)rm * INF + q * 8];
    const uint4* wf = (const uint4*)W1f;

#pragma unroll
    for (int hf = 0; hf < 2; ++hf) {
        float4 xv[8];
#pragma unroll
        for (int t = 0; t < 4; ++t) {
            xv[2 * t]     = *(const float4*)(xp + (hf * 4 + t) * 32);
            xv[2 * t + 1] = *(const float4*)(xp + (hf * 4 + t) * 32 + 4);
        }
        short8 af[4];
#pragma unroll
        for (int t = 0; t < 4; ++t) {
            af[t][0] = (short)f2bf(xv[2 * t].x);
            af[t][1] = (short)f2bf(xv[2 * t].y);
            af[t][2] = (short)f2bf(xv[2 * t].z);
            af[t][3] = (short)f2bf(xv[2 * t].w);
            af[t][4] = (short)f2bf(xv[2 * t + 1].x);
            af[t][5] = (short)f2bf(xv[2 * t + 1].y);
            af[t][6] = (short)f2bf(xv[2 * t + 1].z);
            af[t][7] = (short)f2bf(xv[2 * t + 1].w);
        }
#pragma unroll
        for (int ks = 0; ks < 4; ++ks) {
#pragma unroll
            for (int ct = 0; ct < 8; ++ct) {
                union { uint4 u; short8 s; } bv;
                bv.u = wf[(size_t)((hf * 4 + ks) * 8 + ct) * 64 + lane];
                acc[ct] = __builtin_amdgcn_mfma_f32_16x16x32_bf16(af[ks], bv.s, acc[ct], 0, 0, 0);
            }
        }
    }

#pragma unroll
    for (int reg = 0; reg < 4; ++reg) {
        int r = r0 + q * 4 + reg;
        if (r < NN) {
            float s = isq_s[r];
#pragma unroll
            for (int ct = 0; ct < 8; ++ct)
                H[((size_t)ct * NN + r) * 16 + ln] = (ushort_t)f2bf(acc[ct][reg] * s);
        }
    }
}

// unpack-accumulate one 16B slice (8 bf16 feats) into a[0..7]
#define ACC8(v) { a[0] += bflo((v).x); a[1] += bfhi((v).x); \
                  a[2] += bflo((v).y); a[3] += bfhi((v).y); \
                  a[4] += bflo((v).z); a[5] += bfhi((v).z); \
                  a[6] += bflo((v).w); a[7] += bfhi((v).w); }

// ---- layer-1 aggregate, FEATURE-SLICED for per-XCD L2 residency ----
// bid = chunk*8 + slice; bid%8 -> XCD (round-robin), so each XCD works one
// 3.2MB slice table (fits 4MB L2): random gathers become L2 hits. Per-edge
// VALU work identical to the fused form (8 slices x 2 lanes x 16 ops).
// Bias/ReLU are feature-local -> h1 slice finished in-place, bf16.
__launch_bounds__(256)
__global__ void k_agg1s(const int* __restrict__ row_ptr, const int* __restrict__ srcs,
                        const uint4* __restrict__ Hfs, const float* __restrict__ isq_d,
                        const float* __restrict__ b1, uint4* __restrict__ h1fs) {
    const int wv = threadIdx.x >> 6;
    const int lane = threadIdx.x & 63;
    const int hl = (lane >> 5) & 1;    // node within wave pair
    const int slot = (lane >> 1) & 15; // edge slot 0..15
    const int half = lane & 1;         // 16B half of the 32B slice row
    const int sl = blockIdx.x & 7;     // feature slice 0..7 == XCD (heuristic)
    const int chunk = blockIdx.x >> 3; // 0..1249, 80 nodes each (1250*80==NN)
    const size_t base = (size_t)sl * NN;

    for (int pass = 0; pass < 10; ++pass) {
        const int n = chunk * 80 + pass * 8 + wv * 2 + hl;
        float a[8];
#pragma unroll
        for (int k = 0; k < 8; ++k) a[k] = 0.0f;

        int beg = row_ptr[n], end = row_ptr[n + 1];
        int j = beg;
        for (; j + 32 <= end; j += 32) {       // 32 edges, 2 loads in flight
            int sA = srcs[j + slot];
            int sB = srcs[j + 16 + slot];
            uint4 vA = Hfs[(base + sA) * 2 + half];
            uint4 vB = Hfs[(base + sB) * 2 + half];
            ACC8(vA); ACC8(vB);
        }
        if (j + 16 <= end) {
            uint4 v = Hfs[(base + srcs[j + slot]) * 2 + half];
            ACC8(v);
            j += 16;
        }
        int rem = end - j;                      // 0..15 tail edges
        if (slot < rem) {
            uint4 v = Hfs[(base + srcs[j + slot]) * 2 + half];
            ACC8(v);
        }
        // reduce across slot (lane bits 1..4); hl (bit5) and half (bit0) kept
#pragma unroll
        for (int k = 0; k < 8; ++k) {
            a[k] += __shfl_xor(a[k], 2);
            a[k] += __shfl_xor(a[k], 4);
            a[k] += __shfl_xor(a[k], 8);
            a[k] += __shfl_xor(a[k], 16);
        }
        if (slot == 0) {
            float sc = isq_d[n];
            const int f0 = sl * 16 + half * 8;
            float4 ba = *(const float4*)&b1[f0];
            float4 bb = *(const float4*)&b1[f0 + 4];
            uint_t p0 = f2bf(fmaxf(a[0] * sc + ba.x, 0.0f))
                      | (f2bf(fmaxf(a[1] * sc + ba.y, 0.0f)) << 16);
            uint_t p1 = f2bf(fmaxf(a[2] * sc + ba.z, 0.0f))
                      | (f2bf(fmaxf(a[3] * sc + ba.w, 0.0f)) << 16);
            uint_t p2 = f2bf(fmaxf(a[4] * sc + bb.x, 0.0f))
                      | (f2bf(fmaxf(a[5] * sc + bb.y, 0.0f)) << 16);
            uint_t p3 = f2bf(fmaxf(a[6] * sc + bb.z, 0.0f))
                      | (f2bf(fmaxf(a[7] * sc + bb.w, 0.0f)) << 16);
            h1fs[(base + n) * 2 + half] = (uint4){p0, p1, p2, p3};
        }
    }
}

// ---- GEMM2 (MFMA): H2b[N,40](bf16) = (h1 @ W2) * isq_s, h1 slice-major ----
__launch_bounds__(256)
__global__ void k_gemm2(const uint4* __restrict__ h1fs, const ushort_t* __restrict__ W2f,
                        const float* __restrict__ isq_s, ushort_t* __restrict__ H2b) {
    const int wv = threadIdx.x >> 6;
    const int lane = threadIdx.x & 63;
    const int ln = lane & 15;
    const int q  = lane >> 4;
    const int r0 = blockIdx.x * 64 + wv * 16;
    const int rm = min(r0 + ln, NN - 1);      // A row for this lane

    f32x4 acc[3];
#pragma unroll
    for (int ct = 0; ct < 3; ++ct) acc[ct] = (f32x4){0.f, 0.f, 0.f, 0.f};

    const uint4* wf = (const uint4*)W2f;
#pragma unroll
    for (int ks = 0; ks < 4; ++ks) {
        union { uint4 u; short8 s; } av;
        const int sl2 = ks * 2 + (q >> 1);
        av.u = h1fs[((size_t)sl2 * NN + rm) * 2 + (q & 1)];
#pragma unroll
        for (int ct = 0; ct < 3; ++ct) {
            union { uint4 u; short8 s; } bv;
            bv.u = wf[(size_t)(ks * 3 + ct) * 64 + lane];
            acc[ct] = __builtin_amdgcn_mfma_f32_16x16x32_bf16(av.s, bv.s, acc[ct], 0, 0, 0);
        }
    }

#pragma unroll
    for (int ct = 0; ct < 3; ++ct) {
        const int c = ct * 16 + ln;
        if (c < NC) {
#pragma unroll
            for (int reg = 0; reg < 4; ++reg) {
                int rg = r0 + q * 4 + reg;
                if (rg < NN)
                    H2b[(size_t)rg * NC + c] = (ushort_t)f2bf(acc[ct][reg] * isq_s[rg]);
            }
        }
    }
}

// ---- gather2 v3: 5 lanes x uint4 per edge (80B row), 12 edge slots ----
__launch_bounds__(256)
__global__ void k_gather2(const int* __restrict__ row_ptr, const int* __restrict__ srcs,
                          const uint4* __restrict__ H2b4, const float* __restrict__ isq_d,
                          const float* __restrict__ b2, float* __restrict__ out) {
    __shared__ float pt[4][64][9];   // 9.2 KB, stride-9 pad (2-way aliasing only)
    const int wv = threadIdx.x >> 6;
    const int lane = threadIdx.x & 63;
    const int grp = lane / 5;        // 0..11 active edge slots; 12 = idle lanes 60-63
    const int gl  = lane - grp * 5;  // uint4 index within the 80B row
    const int n = blockIdx.x * 4 + wv;

    float a[8];
#pragma unroll
    for (int k = 0; k < 8; ++k) a[k] = 0.0f;

    if (n < NN && grp < 12) {
        int beg = row_ptr[n], end = row_ptr[n + 1];
        int j = beg;
        for (; j + 24 <= end; j += 24) {            // 24 edges, 2 loads in flight
            int sA = srcs[j + grp];
            int sB = srcs[j + 12 + grp];
            uint4 vA = H2b4[(size_t)sA * 5 + gl];
            uint4 vB = H2b4[(size_t)sB * 5 + gl];
            ACC8(vA); ACC8(vB);
        }
        if (j + 12 <= end) {                         // 12-edge tier
            uint4 v = H2b4[(size_t)srcs[j + grp] * 5 + gl];
            ACC8(v);
            j += 12;
        }
        int r = end - j;                             // 0..11 tail edges
        if (grp < r) {
            uint4 v = H2b4[(size_t)srcs[j + grp] * 5 + gl];
            ACC8(v);
        }
    }
#pragma unroll
    for (int k = 0; k < 8; ++k) pt[wv][lane][k] = a[k];
    __syncthreads();

    if (n < NN && lane < NC) {
        const int g2 = lane >> 3;    // which uint4 slice (0..4)
        const int i2 = lane & 7;     // feat within slice
        float s = 0.0f;
#pragma unroll
        for (int g = 0; g < 12; ++g)
            s += pt[wv][g * 5 + g2][i2];
        out[(size_t)n * NC + lane] = s * isq_d[n] + b2[lane];
    }
}

extern "C" void kernel_launch(void* const* d_in, const int* in_sizes, int n_in,
                              void* d_out, int out_size, void* d_ws, size_t ws_size,
                              hipStream_t stream) {
    const float* X  = (const float*)d_in[0];
    const int* src  = (const int*)d_in[1];
    const int* dst  = (const int*)d_in[2];
    const float* W1 = (const float*)d_in[3];
    const float* b1 = (const float*)d_in[4];
    const float* W2 = (const float*)d_in[5];
    const float* b2 = (const float*)d_in[6];
    float* out = (float*)d_out;

    // workspace layout in 4-byte words; peak = 16,724,608 words = 63.8 MiB
    int* w = (int*)d_ws;
    uint_t* cursA   = (uint_t*)w;                  // 1568
    uint_t* cursB   = cursA + NBUK;                // 1568   (total 3136, pad to 4096)
    float* isq_s    = (float*)(w + 4096);          // NNP
    float* isq_d    = isq_s + NNP;                 // NNP
    int* row_ptr    = (int*)(isq_d + NNP);         // NNP (row_ptr[NN] valid)
    ushort_t* W1f   = (ushort_t*)(row_ptr + NNP);              // 32768 bf16 (16384 words)
    ushort_t* W2f   = (ushort_t*)(row_ptr + NNP + 16384);      // 6144 bf16 (3072 words)
    int* Hw         = row_ptr + NNP + 19456;       // Hfs region base (16B aligned)
    uint_t* edgesA  = (uint_t*)Hw;                 // NBUK*SA words -- dead after bfinish
    uchar_t* bytesB = (uchar_t*)(Hw + NBUK * SA);  // NBUK*SB bytes -- dead after bfinish
    ushort_t* Hfs   = (ushort_t*)Hw;               // 8 x NN x 16 bf16 = 6.4M words
    int* srcs       = Hw + 6400000;                // NE words (compact, node-sorted)
    ushort_t* H2b   = (ushort_t*)(srcs + NE);      // NN*40 bf16 = 2M words (16B aligned)
    uint4* h1fs     = (uint4*)(srcs + NE + 2000000); // 8 x NN x 16 bf16 = 6.4M words

    // CSR build: strided bucket windows, 64-node buckets
    k_binit <<<(NBUK + 255) / 256, 256, 0, stream>>>(cursA, cursB);
    k_bfill <<<NBLK, 1024, 0, stream>>>(src, dst, cursA, cursB, edgesA, bytesB,
                                        W1, W1f, W2, W2f);
    k_bfinish<<<NBUK, 256, 0, stream>>>(cursA, cursB, edgesA, bytesB,
                                        row_ptr, srcs, isq_d, isq_s);

    // layer 1 GEMM (MFMA), slice-major H  [overwrites edgesA/bytesB]
    k_gemm1<<<(NN + 63) / 64, 256, 0, stream>>>(X, W1f, isq_s, Hfs);

    // layer-1 aggregate: feature-sliced, per-XCD L2-resident gather
    k_agg1s<<<(NN / 80) * 8, 256, 0, stream>>>(row_ptr, srcs, (const uint4*)Hfs,
                                               isq_d, b1, h1fs);

    // layer 2 GEMM (MFMA): h1 @ W2 -> bf16 H2b
    k_gemm2<<<(NN + 63) / 64, 256, 0, stream>>>((const uint4*)h1fs, W2f, isq_s, H2b);

    // layer-2 aggregate + bias -> fp32 out
    k_gather2<<<(NN + 3) / 4, 256, 0, stream>>>(row_ptr, srcs, (const uint4*)H2b,
                                                isq_d, b2, out);
}

// Round 12
// 338.232 us; speedup vs baseline: 1.2680x; 1.2680x over previous
//
#include <hip/hip_runtime.h>
#include <hip/hip_bf16.h>
#include <stdint.h>

#define NN 100000      // nodes
#define NE 1600000     // edges
#define INF 256        // in feats
#define HF 128         // hidden feats
#define NC 40          // classes
#define NNP 100352     // NN padded to multiple of 512
#define NBUK 1568      // NNP / 64 buckets (64 nodes per bucket)
#define BKSH 6         // bucket = node >> 6
#define NBLK 256       // blocks for bfill (all CUs)
#define CHUNK 6250     // edges per block (256 * 6250 == NE)
#define SA 1536        // edgesA words per bucket window (mean 1021, 16 sigma)
#define SB 1536        // bytesB bytes per bucket window

typedef unsigned short ushort_t;
typedef unsigned int uint_t;
typedef unsigned char uchar_t;
typedef __attribute__((ext_vector_type(8))) short short8;   // 8 bf16 (4 VGPR)
typedef __attribute__((ext_vector_type(4))) float f32x4;

__device__ __forceinline__ float bflo(uint_t u) {
    union { uint_t i; float f; } v; v.i = u << 16; return v.f;
}
__device__ __forceinline__ float bfhi(uint_t u) {
    union { uint_t i; float f; } v; v.i = u & 0xffff0000u; return v.f;
}
__device__ __forceinline__ uint_t f2bf(float f) {
    __hip_bfloat16 h = __float2bfloat16(f);
    return (uint_t)*reinterpret_cast<ushort_t*>(&h);
}

// ---- bucket scatter into strided windows + W1/W2 fragment conversion ----
// cursors hold per-bucket COUNTS (memset to 0); claim position = t*SA + old.
// 1024 threads/block (16 waves/CU): pure gather/scatter latency kernel.
// W1f layout: (k,n) -> (((ks*8+ct)*4+q)*16+ln)*8 + j  (ks=k/32,q=(k/8)%4,j=k%8,ct=n/16,ln=n&15)
// W2f layout: K=128, N padded 40->48: (((ks*3+ct)*4+q)*16+ln)*8 + j
__launch_bounds__(1024)
__global__ void k_bfill(const int* __restrict__ src, const int* __restrict__ dst,
                        uint_t* __restrict__ cursA, uint_t* __restrict__ cursB,
                        uint_t* __restrict__ edgesA, uchar_t* __restrict__ bytesB,
                        const float* __restrict__ W1, ushort_t* __restrict__ W1f,
                        const float* __restrict__ W2, ushort_t* __restrict__ W2f) {
    __shared__ uint_t hA[NBUK], hB[NBUK];   // 12.5 KB
    for (int t = threadIdx.x; t < NBUK; t += 1024) { hA[t] = 0; hB[t] = 0; }

    // fused one-time weight conversion
    int i = blockIdx.x * 1024 + threadIdx.x;
    if (i < INF * HF) {
        int k = i >> 7, n = i & 127;
        int ks = k >> 5, q = (k >> 3) & 3, j = k & 7;
        int ct = n >> 4, ln = n & 15;
        W1f[(((ks * 8 + ct) * 4 + q) * 16 + ln) * 8 + j] = (ushort_t)f2bf(W1[i]);
    }
    if (i < HF * 48) {
        int k = i / 48, n = i % 48;
        int ks = k >> 5, q = (k >> 3) & 3, j = k & 7;
        int ct = n >> 4, ln = n & 15;
        float v = (n < NC) ? W2[k * NC + n] : 0.0f;
        W2f[(((ks * 3 + ct) * 4 + q) * 16 + ln) * 8 + j] = (ushort_t)f2bf(v);
    }
    __syncthreads();

    const int beg = blockIdx.x * CHUNK, end = beg + CHUNK;
    for (int e = beg + threadIdx.x; e < end; e += 1024) {
        atomicAdd(&hA[(uint_t)dst[e] >> BKSH], 1u);
        atomicAdd(&hB[(uint_t)src[e] >> BKSH], 1u);
    }
    __syncthreads();
    for (int t = threadIdx.x; t < NBUK; t += 1024) {
        uint_t c = hA[t];
        hA[t] = c ? ((uint_t)t * SA + atomicAdd(&cursA[t], c)) : 0;
        c = hB[t];
        hB[t] = c ? ((uint_t)t * SB + atomicAdd(&cursB[t], c)) : 0;
    }
    __syncthreads();
    for (int e = beg + threadIdx.x; e < end; e += 1024) {
        uint_t d = (uint_t)dst[e], s = (uint_t)src[e];
        uint_t pA = atomicAdd(&hA[d >> BKSH], 1u);     // LDS cursor (absolute)
        edgesA[pA] = ((d & 63u) << 17) | s;            // 23-bit packed (dstLow, src)
        uint_t pB = atomicAdd(&hB[s >> BKSH], 1u);     // LDS cursor (absolute)
        bytesB[pB] = (uchar_t)(s & 63u);
    }
}

// ---- per-bucket finish (bscan fused): block-local prefix over cursA counts
//      -> obase; 64-bin hist -> row_ptr/isq_d; LDS counting sort -> compact
//      srcs; B-side 64-bin hist -> isq_s ----
__launch_bounds__(256)
__global__ void k_bfinish(const uint_t* __restrict__ cursA, const uint_t* __restrict__ cursB,
                          const uint_t* __restrict__ edgesA, const uchar_t* __restrict__ bytesB,
                          int* __restrict__ row_ptr, int* __restrict__ srcs,
                          float* __restrict__ isq_d, float* __restrict__ isq_s) {
    __shared__ uint_t red[256];
    __shared__ uint_t h[64], sc[64], cur[64];
    const int b = blockIdx.x, t = threadIdx.x;

    // fused exclusive bucket scan: obase = sum_{i<b} cursA[i]  (counts)
    uint_t acc = 0;
    for (int i = t; i < b; i += 256) acc += cursA[i];
    red[t] = acc;
    __syncthreads();
    for (int off = 128; off > 0; off >>= 1) {
        if (t < off) red[t] += red[t + off];
        __syncthreads();
    }
    const uint_t obase = red[0];

    if (t < 64) h[t] = 0;
    __syncthreads();
    const uint_t begI = (uint_t)b * SA;
    const uint_t endI = begI + cursA[b];
    for (uint_t e = begI + t; e < endI; e += 256)
        atomicAdd(&h[(edgesA[e] >> 17) & 63u], 1u);
    __syncthreads();
    uint_t v = (t < 64) ? h[t] : 0;
    if (t < 64) sc[t] = v;
    __syncthreads();
    for (int off = 1; off < 64; off <<= 1) {
        uint_t tv = (t >= off && t < 64) ? sc[t - off] : 0;
        __syncthreads();
        if (t < 64) sc[t] += tv;
        __syncthreads();
    }
    if (t < 64) {
        uint_t excl = sc[t] - v;
        row_ptr[b * 64 + t] = (int)(obase + excl);
        isq_d[b * 64 + t] = rsqrtf(fmaxf((float)v, 1.0f));
        cur[t] = excl;
    }
    __syncthreads();
    for (uint_t e = begI + t; e < endI; e += 256) {
        uint_t u = edgesA[e];
        uint_t p = atomicAdd(&cur[(u >> 17) & 63u], 1u);
        srcs[obase + p] = (int)(u & 0x1FFFFu);
    }
    __syncthreads();
    if (t < 64) h[t] = 0;
    __syncthreads();
    const uint_t begB = (uint_t)b * SB;
    const uint_t endB = begB + cursB[b];
    for (uint_t e = begB + t; e < endB; e += 256)
        atomicAdd(&h[bytesB[e]], 1u);
    __syncthreads();
    if (t < 64) isq_s[b * 64 + t] = rsqrtf(fmaxf((float)h[t], 1.0f));
}

// ---- GEMM1 (MFMA): H[N,128](bf16) = (X[N,256] @ W1) * isq_s[row] ----
// Two-phase hoist: 8 independent float4 X loads per half (spill-free under
// the 128-VGPR cap), 32 MFMAs per half against L2-hot W1f.
__launch_bounds__(256, 4)
__global__ void k_gemm1(const float* __restrict__ X, const ushort_t* __restrict__ W1f,
                        const float* __restrict__ isq_s, ushort_t* __restrict__ H) {
    const int wv = threadIdx.x >> 6;
    const int lane = threadIdx.x & 63;
    const int ln = lane & 15;
    const int q  = lane >> 4;
    const int r0 = blockIdx.x * 64 + wv * 16;
    const int rm = min(r0 + ln, NN - 1);     // A row for this lane (m = ln)

    f32x4 acc[8];
#pragma unroll
    for (int ct = 0; ct < 8; ++ct) acc[ct] = (f32x4){0.f, 0.f, 0.f, 0.f};

    const float* xp = &X[(size_t)rm * INF + q * 8];
    const uint4* wf = (const uint4*)W1f;

#pragma unroll
    for (int hf = 0; hf < 2; ++hf) {
        float4 xv[8];
#pragma unroll
        for (int t = 0; t < 4; ++t) {
            xv[2 * t]     = *(const float4*)(xp + (hf * 4 + t) * 32);
            xv[2 * t + 1] = *(const float4*)(xp + (hf * 4 + t) * 32 + 4);
        }
        short8 af[4];
#pragma unroll
        for (int t = 0; t < 4; ++t) {
            af[t][0] = (short)f2bf(xv[2 * t].x);
            af[t][1] = (short)f2bf(xv[2 * t].y);
            af[t][2] = (short)f2bf(xv[2 * t].z);
            af[t][3] = (short)f2bf(xv[2 * t].w);
            af[t][4] = (short)f2bf(xv[2 * t + 1].x);
            af[t][5] = (short)f2bf(xv[2 * t + 1].y);
            af[t][6] = (short)f2bf(xv[2 * t + 1].z);
            af[t][7] = (short)f2bf(xv[2 * t + 1].w);
        }
#pragma unroll
        for (int ks = 0; ks < 4; ++ks) {
#pragma unroll
            for (int ct = 0; ct < 8; ++ct) {
                union { uint4 u; short8 s; } bv;
                bv.u = wf[(size_t)((hf * 4 + ks) * 8 + ct) * 64 + lane];
                acc[ct] = __builtin_amdgcn_mfma_f32_16x16x32_bf16(af[ks], bv.s, acc[ct], 0, 0, 0);
            }
        }
    }

#pragma unroll
    for (int reg = 0; reg < 4; ++reg) {
        int r = r0 + q * 4 + reg;
        if (r < NN) {
            float s = isq_s[r];
#pragma unroll
            for (int ct = 0; ct < 8; ++ct)
                H[(size_t)r * HF + ct * 16 + ln] = (ushort_t)f2bf(acc[ct][reg] * s);
        }
    }
}

// unpack-accumulate one 16B slice (8 bf16 feats) into a[0..7]
#define ACC8(v) { a[0] += bflo((v).x); a[1] += bfhi((v).x); \
                  a[2] += bflo((v).y); a[3] += bfhi((v).y); \
                  a[4] += bflo((v).z); a[5] += bfhi((v).z); \
                  a[6] += bflo((v).w); a[7] += bfhi((v).w); }

// ---- fused layer1-aggregate + layer2 GEMM (MFMA form, R5-proven) ----
__launch_bounds__(256)
__global__ void k_agg1_gemm2(const int* __restrict__ row_ptr, const int* __restrict__ srcs,
                             const uint4* __restrict__ H16, const float* __restrict__ isq_d,
                             const float* __restrict__ isq_s, const float* __restrict__ b1,
                             const ushort_t* __restrict__ W2f, ushort_t* __restrict__ H2b) {
    __shared__ uint4 h1s[16][16];   // 4 KB: [local node][swizzled k-slice]
    const int wv = threadIdx.x >> 6;
    const int lane = threadIdx.x & 63;
    const int grp = lane >> 4;   // edge slot 0..3
    const int gl  = lane & 15;   // uint4 index within 256B row
    const int n0 = blockIdx.x * 16;   // 6250 blocks * 16 == NN exactly

    const float4 bva = ((const float4*)b1)[gl * 2];
    const float4 bvb = ((const float4*)b1)[gl * 2 + 1];

    for (int ni = 0; ni < 4; ++ni) {
        const int rl = wv * 4 + ni;        // local node 0..15
        const int n = n0 + rl;
        float a[8];
#pragma unroll
        for (int k = 0; k < 8; ++k) a[k] = 0.0f;

        int beg = row_ptr[n], end = row_ptr[n + 1];
        int j = beg;
        for (; j + 16 <= end; j += 16) {   // 16 edges/iter, 4 KB in flight
            int sA = srcs[j + grp];
            int sB = srcs[j + 4 + grp];
            int sC = srcs[j + 8 + grp];
            int sD = srcs[j + 12 + grp];
            uint4 vA = H16[(size_t)sA * 16 + gl];
            uint4 vB = H16[(size_t)sB * 16 + gl];
            uint4 vC = H16[(size_t)sC * 16 + gl];
            uint4 vD = H16[(size_t)sD * 16 + gl];
            ACC8(vA); ACC8(vB); ACC8(vC); ACC8(vD);
        }
        for (; j + 8 <= end; j += 8) {
            int sA = srcs[j + grp];
            int sB = srcs[j + 4 + grp];
            uint4 vA = H16[(size_t)sA * 16 + gl];
            uint4 vB = H16[(size_t)sB * 16 + gl];
            ACC8(vA); ACC8(vB);
        }
        for (; j + 4 <= end; j += 4) {
            uint4 v = H16[(size_t)srcs[j + grp] * 16 + gl];
            ACC8(v);
        }
        int r = end - j;                   // 0..3 tail edges
        if (grp < r) {
            uint4 v = H16[(size_t)srcs[j + grp] * 16 + gl];
            ACC8(v);
        }
        // combine the 4 edge-slot partials (lane bits 4 and 5)
#pragma unroll
        for (int k = 0; k < 8; ++k) {
            a[k] += __shfl_xor(a[k], 16);
            a[k] += __shfl_xor(a[k], 32);
        }
        if (lane < 16) {
            float sc = isq_d[n];
            uint_t p0 = f2bf(fmaxf(a[0] * sc + bva.x, 0.0f))
                      | (f2bf(fmaxf(a[1] * sc + bva.y, 0.0f)) << 16);
            uint_t p1 = f2bf(fmaxf(a[2] * sc + bva.z, 0.0f))
                      | (f2bf(fmaxf(a[3] * sc + bva.w, 0.0f)) << 16);
            uint_t p2 = f2bf(fmaxf(a[4] * sc + bvb.x, 0.0f))
                      | (f2bf(fmaxf(a[5] * sc + bvb.y, 0.0f)) << 16);
            uint_t p3 = f2bf(fmaxf(a[6] * sc + bvb.z, 0.0f))
                      | (f2bf(fmaxf(a[7] * sc + bvb.w, 0.0f)) << 16);
            h1s[rl][gl ^ rl] = (uint4){p0, p1, p2, p3};   // XOR-swizzle vs row
        }
    }
    __syncthreads();

    // GEMM2: waves 0-2 each own one 16-col tile (N padded 40->48)
    if (wv < 3) {
        const int q = grp;     // lane>>4
        const int ln = gl;     // lane&15; A row (= local node) for this lane
        f32x4 acc = (f32x4){0.f, 0.f, 0.f, 0.f};
        const uint4* wf = (const uint4*)W2f;
#pragma unroll
        for (int ks = 0; ks < 4; ++ks) {
            union { uint4 u; short8 s; } av, bv;
            av.u = h1s[ln][(ks * 4 + q) ^ ln];            // matching swizzle
            bv.u = wf[(size_t)(ks * 3 + wv) * 64 + lane];
            acc = __builtin_amdgcn_mfma_f32_16x16x32_bf16(av.s, bv.s, acc, 0, 0, 0);
        }
        int c = wv * 16 + ln;
        if (c < NC) {
#pragma unroll
            for (int reg = 0; reg < 4; ++reg) {
                int rg = n0 + q * 4 + reg;
                H2b[(size_t)rg * NC + c] = (ushort_t)f2bf(acc[reg] * isq_s[rg]);
            }
        }
    }
}

// ---- gather2 v3: 5 lanes x uint4 per edge (80B row), 12 edge slots ----
__launch_bounds__(256)
__global__ void k_gather2(const int* __restrict__ row_ptr, const int* __restrict__ srcs,
                          const uint4* __restrict__ H2b4, const float* __restrict__ isq_d,
                          const float* __restrict__ b2, float* __restrict__ out) {
    __shared__ float pt[4][64][9];   // 9.2 KB, stride-9 pad (2-way aliasing only)
    const int wv = threadIdx.x >> 6;
    const int lane = threadIdx.x & 63;
    const int grp = lane / 5;        // 0..11 active edge slots; 12 = idle lanes 60-63
    const int gl  = lane - grp * 5;  // uint4 index within the 80B row
    const int n = blockIdx.x * 4 + wv;

    float a[8];
#pragma unroll
    for (int k = 0; k < 8; ++k) a[k] = 0.0f;

    if (n < NN && grp < 12) {
        int beg = row_ptr[n], end = row_ptr[n + 1];
        int j = beg;
        for (; j + 24 <= end; j += 24) {            // 24 edges, 2 loads in flight
            int sA = srcs[j + grp];
            int sB = srcs[j + 12 + grp];
            uint4 vA = H2b4[(size_t)sA * 5 + gl];
            uint4 vB = H2b4[(size_t)sB * 5 + gl];
            ACC8(vA); ACC8(vB);
        }
        if (j + 12 <= end) {                         // 12-edge tier
            uint4 v = H2b4[(size_t)srcs[j + grp] * 5 + gl];
            ACC8(v);
            j += 12;
        }
        int r = end - j;                             // 0..11 tail edges
        if (grp < r) {
            uint4 v = H2b4[(size_t)srcs[j + grp] * 5 + gl];
            ACC8(v);
        }
    }
#pragma unroll
    for (int k = 0; k < 8; ++k) pt[wv][lane][k] = a[k];
    __syncthreads();

    if (n < NN && lane < NC) {
        const int g2 = lane >> 3;    // which uint4 slice (0..4)
        const int i2 = lane & 7;     // feat within slice
        float s = 0.0f;
#pragma unroll
        for (int g = 0; g < 12; ++g)
            s += pt[wv][g * 5 + g2][i2];
        out[(size_t)n * NC + lane] = s * isq_d[n] + b2[lane];
    }
}

extern "C" void kernel_launch(void* const* d_in, const int* in_sizes, int n_in,
                              void* d_out, int out_size, void* d_ws, size_t ws_size,
                              hipStream_t stream) {
    const float* X  = (const float*)d_in[0];
    const int* src  = (const int*)d_in[1];
    const int* dst  = (const int*)d_in[2];
    const float* W1 = (const float*)d_in[3];
    const float* b1 = (const float*)d_in[4];
    const float* W2 = (const float*)d_in[5];
    const float* b2 = (const float*)d_in[6];
    float* out = (float*)d_out;

    // workspace layout in 4-byte words; peak = 10,324,608 words = 39.4 MiB
    int* w = (int*)d_ws;
    uint_t* cursA   = (uint_t*)w;                  // 1568 (counts)
    uint_t* cursB   = cursA + NBUK;                // 1568 (counts; total 3136, pad 4096)
    float* isq_s    = (float*)(w + 4096);          // NNP
    float* isq_d    = isq_s + NNP;                 // NNP
    int* row_ptr    = (int*)(isq_d + NNP);         // NNP (row_ptr[NN] valid)
    ushort_t* W1f   = (ushort_t*)(row_ptr + NNP);              // 32768 bf16 (16384 words)
    ushort_t* W2f   = (ushort_t*)(row_ptr + NNP + 16384);      // 6144 bf16 (3072 words)
    int* Hw         = row_ptr + NNP + 19456;       // H region base (16B aligned)
    uint_t* edgesA  = (uint_t*)Hw;                 // NBUK*SA words (strided) -- dead after bfinish
    uchar_t* bytesB = (uchar_t*)(Hw + NBUK * SA);  // NBUK*SB bytes (strided) -- dead after bfinish
    ushort_t* H     = (ushort_t*)Hw;               // NN*128 bf16 = 6.4M words (overlaps both)
    int* srcs       = Hw + 6400000;                // NE words (compact, node-sorted)
    ushort_t* H2b   = (ushort_t*)(srcs + NE);      // NN*40 bf16 = 2M words (16B aligned)

    // CSR build: strided bucket windows, 64-node buckets
    hipMemsetAsync(cursA, 0, 2 * NBUK * sizeof(uint_t), stream);
    k_bfill <<<NBLK, 1024, 0, stream>>>(src, dst, cursA, cursB, edgesA, bytesB,
                                        W1, W1f, W2, W2f);
    k_bfinish<<<NBUK, 256, 0, stream>>>(cursA, cursB, edgesA, bytesB,
                                        row_ptr, srcs, isq_d, isq_s);

    // layer 1 GEMM (MFMA)  [H overwrites edgesA/bytesB -- both dead now]
    k_gemm1<<<(NN + 63) / 64, 256, 0, stream>>>(X, W1f, isq_s, H);

    // fused: layer-1 aggregate + bias/relu + layer-2 GEMM (MFMA) -> bf16 H2
    k_agg1_gemm2<<<NN / 16, 256, 0, stream>>>(row_ptr, srcs, (const uint4*)H,
                                              isq_d, isq_s, b1, W2f, H2b);

    // layer-2 aggregate + bias -> fp32 out
    k_gather2<<<(NN + 3) / 4, 256, 0, stream>>>(row_ptr, srcs, (const uint4*)H2b,
                                                isq_d, b2, out);
}